// Round 7
// baseline (10610.857 us; speedup 1.0000x reference)
//
#include <hip/hip_runtime.h>
#include <math.h>

#define MC      50000
#define MPATHS  100000   // 2*MC antithetic
#define NSTEPS  180
#define NOPTS   32

typedef _Float16 half2v __attribute__((ext_vector_type(2)));
typedef unsigned u32x32 __attribute__((ext_vector_type(32)));

// v_dot2_f32_f16: c += a.x*b.x + a.y*b.y (per-lane, layout-free)
static __device__ __forceinline__ float fdot2(unsigned w, unsigned h, float c) {
    return __builtin_amdgcn_fdot2(__builtin_bit_cast(half2v, w),
                                  __builtin_bit_cast(half2v, h), c, false);
}
// RNE f16 pair pack (pre-kernel only)
static __device__ __forceinline__ unsigned pkh2(float a, float b) {
    half2v h; h.x = (_Float16)a; h.y = (_Float16)b;   // .x = low half
    return __builtin_bit_cast(unsigned, h);
}
// fast RTZ pack (main loop, per-step inputs); builtin returns __fp16x2 -> bit_cast
static __device__ __forceinline__ unsigned pkrtz(float a, float b) {
    auto h = __builtin_amdgcn_cvt_pkrtz(a, b);
    return __builtin_bit_cast(unsigned, h);
}

// pack W1 (4x64x4) and W2 (4x64x64) f32 -> f16x2 pairs (natural pair order)
__global__ void pack_w(const float* __restrict__ W1, const float* __restrict__ W2,
                       unsigned* __restrict__ wp1, unsigned* __restrict__ wp2) {
    int i = blockIdx.x * 256 + threadIdx.x;
    if (i < 512)              wp1[i] = pkh2(W1[2 * i], W1[2 * i + 1]);
    else if (i < 512 + 8192) { int k = i - 512; wp2[k] = pkh2(W2[2 * k], W2[2 * k + 1]); }
}

// Block = 256 threads = 4 waves over the SAME 64 paths; wave w evaluates net w
// (wave-uniform weights -> s_load). Per step: 1-KB double-buffered LDS exchange
// of the 4 net outputs + one barrier; every wave redundantly updates S,V.
// 4x resident waves vs round-6 -> hides scalar-cache/L2 miss latency.
__global__ __launch_bounds__(256)
void sde_dot2(const float* __restrict__ x,
              const float* __restrict__ z,
              const float* __restrict__ z1,
              const float* __restrict__ b1, const float* __restrict__ b2,
              const float* __restrict__ Wo, const float* __restrict__ bo,
              const unsigned* __restrict__ wp1,
              const unsigned* __restrict__ wp2,
              float* __restrict__ acc)
{
    __shared__ float o_sh[2][4][64];
    __shared__ float ls_k[NOPTS];
    __shared__ int   maskTab[NSTEPS + 4];

    const int tid  = threadIdx.x;
    const int lane = tid & 63;
    const int wid  = __builtin_amdgcn_readfirstlane(tid >> 6);  // net id, scalar

    for (int jj = tid; jj < NSTEPS + 4; jj += 256) maskTab[jj] = 0;
    if (tid < NOPTS) ls_k[tid] = x[2 * tid + 1];
    __syncthreads();
    if (tid < NOPTS) atomicOr(&maskTab[(int)x[2 * tid]], 1 << tid);
    __syncthreads();

    const int p_ = blockIdx.x * 64 + lane;
    const float wgt = (p_ < MPATHS) ? 1.0f : 0.0f;    // ghost lanes weightless
    int pc = (p_ < MPATHS) ? p_ : (MPATHS - 1);
    float sgn = 1.0f; int row = pc;
    if (pc >= MC) { sgn = -1.0f; row -= MC; }
    const float* __restrict__ zrow  = z  + (size_t)row * NSTEPS;
    const float* __restrict__ z1row = z1 + (size_t)row * NSTEPS;

    const float hh   = 1.0f / 360.0f;
    const float sqh  = sqrtf(hh);
    const float s75  = 0.86602540378443864676f;
    const float rate = 0.025f;

    // this wave's net
    const float*    __restrict__ b1n  = b1  + wid * 64;
    const float*    __restrict__ b2n  = b2  + wid * 64;
    const float*    __restrict__ won  = Wo  + wid * 64;
    const unsigned* __restrict__ wp1n = wp1 + wid * 128;
    const unsigned* __restrict__ wp2n = wp2 + wid * 2048;
    const float bon = bo[wid];

    float S = 100.0f, V = 0.04f;

    #pragma unroll 1
    for (int i = 0; i < NSTEPS; ++i) {
        const float zcr = zrow[i];
        const float z1r = z1row[i];
        const float dW  = sqh * (sgn * zcr);
        const float dW1 = sqh * (sgn * (-0.5f * zcr + s75 * z1r));
        const float t   = (float)i * hh;

        const unsigned in01 = pkrtz(t, S);     // (t, S)
        const unsigned in23 = pkrtz(V, rate);  // (V, rate)

        // ---- layer 1 (dot2) -> packed f16 h1 in an SSA vector ----
        u32x32 h1p;
        #pragma unroll
        for (int u = 0; u < 64; u += 2) {
            float a0 = fdot2(wp1n[2 * u + 0], in01, b1n[u]);
            a0 = fdot2(wp1n[2 * u + 1], in23, a0);
            float a1 = fdot2(wp1n[2 * u + 2], in01, b1n[u + 1]);
            a1 = fdot2(wp1n[2 * u + 3], in23, a1);
            h1p[u >> 1] = pkrtz(fmaxf(a0, 0.0f), fmaxf(a1, 0.0f));
        }

        // ---- layer 2 (dot2, fully unrolled) + fused output layer ----
        float outn = bon;
        #pragma unroll
        for (int j = 0; j < 64; j += 4) {
            const unsigned* __restrict__ wr = wp2n + j * 32;
            float a0 = b2n[j + 0];
            float a1 = b2n[j + 1];
            float a2 = b2n[j + 2];
            float a3 = b2n[j + 3];
            #pragma unroll
            for (int k2 = 0; k2 < 32; ++k2) {
                const unsigned hv = h1p[k2];
                a0 = fdot2(wr[k2],      hv, a0);
                a1 = fdot2(wr[32 + k2], hv, a1);
                a2 = fdot2(wr[64 + k2], hv, a2);
                a3 = fdot2(wr[96 + k2], hv, a3);
            }
            outn = fmaf(won[j + 0], fmaxf(a0, 0.0f), outn);
            outn = fmaf(won[j + 1], fmaxf(a1, 0.0f), outn);
            outn = fmaf(won[j + 2], fmaxf(a2, 0.0f), outn);
            outn = fmaf(won[j + 3], fmaxf(a3, 0.0f), outn);
        }

        // ---- exchange net outputs (double-buffered, 1 barrier/step) ----
        const int buf = i & 1;
        o_sh[buf][wid][lane] = outn;
        __syncthreads();
        const float o0 = o_sh[buf][0][lane];
        const float o1 = o_sh[buf][1][lane];
        const float o2 = o_sh[buf][2][lane];
        const float o3 = o_sh[buf][3][lane];

        // route: 0=driftS, 1=diffS, 2=driftV, 3=diffV (redundant in all waves)
        S = fmaxf(fmaf(o0, hh, fmaf(o1, dW,  S)), 0.0f);
        V = fmaxf(fmaf(o2, hh, fmaf(o3, dW1, V)), 0.0f);

        // ---- on-the-fly payoff at maturities (wave 0 only) ----
        if (wid == 0) {
            int mm = maskTab[i + 1];
            while (mm) {
                int qq = __ffs(mm) - 1; mm &= mm - 1;
                float pay = wgt * fmaxf(S - ls_k[qq], 0.0f);
                #pragma unroll
                for (int off = 32; off > 0; off >>= 1)
                    pay += __shfl_down(pay, off, 64);
                if (lane == 0) atomicAdd(&acc[qq], pay);
            }
        }
    }
}

__global__ void price_kernel(const float* __restrict__ x,
                             const float* __restrict__ acc,
                             float* __restrict__ out)
{
    const int q = threadIdx.x;
    if (q < NOPTS) {
        const float mat = x[q * 2];
        const float disc = expf((-0.025f * mat) / 360.0f);
        out[q] = acc[q] * (1.0f / (float)MPATHS) * disc;
    }
}

extern "C" void kernel_launch(void* const* d_in, const int* in_sizes, int n_in,
                              void* d_out, int out_size, void* d_ws, size_t ws_size,
                              hipStream_t stream)
{
    const float* x  = (const float*)d_in[0];
    const float* z  = (const float*)d_in[1];
    const float* z1 = (const float*)d_in[2];
    const float* W1 = (const float*)d_in[3];
    const float* b1 = (const float*)d_in[4];
    const float* W2 = (const float*)d_in[5];
    const float* b2 = (const float*)d_in[6];
    const float* Wo = (const float*)d_in[7];
    const float* bo = (const float*)d_in[8];

    float*    acc = (float*)d_ws;                      // 128B accumulators
    unsigned* wp1 = (unsigned*)((char*)d_ws + 256);    // 2KB  packed W1
    unsigned* wp2 = wp1 + 512;                         // 32KB packed W2

    (void)hipMemsetAsync(acc, 0, NOPTS * sizeof(float), stream);
    pack_w<<<(512 + 8192 + 255) / 256, 256, 0, stream>>>(W1, W2, wp1, wp2);

    const int grid = (MPATHS + 63) / 64;   // 1563 blocks x 4 waves (net-split)
    sde_dot2<<<grid, 256, 0, stream>>>(x, z, z1, b1, b2, Wo, bo, wp1, wp2, acc);
    price_kernel<<<1, 64, 0, stream>>>(x, acc, (float*)d_out);
}

// Round 8
// 9220.883 us; speedup vs baseline: 1.1507x; 1.1507x over previous
//
#include <hip/hip_runtime.h>
#include <math.h>

#define MC      50000
#define MPATHS  100000   // 2*MC antithetic
#define NSTEPS  180
#define NOPTS   32

typedef _Float16 half2v __attribute__((ext_vector_type(2)));
typedef unsigned u32x32 __attribute__((ext_vector_type(32)));

// v_dot2_f32_f16: c += a.x*b.x + a.y*b.y (per-lane, layout-free)
static __device__ __forceinline__ float fdot2(unsigned w, unsigned h, float c) {
    return __builtin_amdgcn_fdot2(__builtin_bit_cast(half2v, w),
                                  __builtin_bit_cast(half2v, h), c, false);
}
// RNE f16 pair pack (pre-kernel only)
static __device__ __forceinline__ unsigned pkh2(float a, float b) {
    half2v h; h.x = (_Float16)a; h.y = (_Float16)b;   // .x = low half
    return __builtin_bit_cast(unsigned, h);
}
// fast RTZ pack (main loop, per-step inputs)
static __device__ __forceinline__ unsigned pkrtz(float a, float b) {
    auto h = __builtin_amdgcn_cvt_pkrtz(a, b);
    return __builtin_bit_cast(unsigned, h);
}

// pack W1 (4x64x4) and W2 (4x64x64) f32 -> f16x2 pairs (natural pair order)
__global__ void pack_w(const float* __restrict__ W1, const float* __restrict__ W2,
                       unsigned* __restrict__ wp1, unsigned* __restrict__ wp2) {
    int i = blockIdx.x * 256 + threadIdx.x;
    if (i < 512)              wp1[i] = pkh2(W1[2 * i], W1[2 * i + 1]);
    else if (i < 512 + 8192) { int k = i - 512; wp2[k] = pkh2(W2[2 * k], W2[2 * k + 1]); }
}

// Block = 256 threads = 4 INDEPENDENT waves (round-6 structure: each wave owns
// 64 paths and evaluates all 4 nets; no barriers in the step loop). All packed
// weights staged once in LDS (34.8KB); layer-2 reads are ds_read_b128 of 4
// weight-pairs at a wave-uniform address = conflict-free broadcast, deep LGKM
// queue -> kills the scalar-cache-miss serialization seen in round 6.
__global__ __launch_bounds__(256, 3)
void sde_dot2(const float* __restrict__ x,
              const float* __restrict__ z,
              const float* __restrict__ z1,
              const float* __restrict__ b1, const float* __restrict__ b2,
              const float* __restrict__ Wo, const float* __restrict__ bo,
              const unsigned* __restrict__ wp1,
              const unsigned* __restrict__ wp2,
              float* __restrict__ acc)
{
    // [0,128): W1 pairs (net n at n*32) ; [128,2176): W2 (net n row j at 128+n*512+j*8)
    __shared__ __align__(16) uint4 wlds[2176];
    __shared__ float ls_k[NOPTS];
    __shared__ int   maskTab[NSTEPS + 4];

    const int tid  = threadIdx.x;
    const int lane = tid & 63;

    // ---- stage weights + option table (once per block) ----
    {
        const uint4* __restrict__ wg1 = (const uint4*)wp1;
        const uint4* __restrict__ wg2 = (const uint4*)wp2;
        if (tid < 128) wlds[tid] = wg1[tid];
        for (int j2 = tid; j2 < 2048; j2 += 256) wlds[128 + j2] = wg2[j2];
    }
    for (int jj = tid; jj < NSTEPS + 4; jj += 256) maskTab[jj] = 0;
    if (tid < NOPTS) ls_k[tid] = x[2 * tid + 1];
    __syncthreads();
    if (tid < NOPTS) atomicOr(&maskTab[(int)x[2 * tid]], 1 << tid);
    __syncthreads();

    // ---- per-path state (each thread = one path) ----
    const int p_ = blockIdx.x * 256 + tid;
    const float wgt = (p_ < MPATHS) ? 1.0f : 0.0f;    // ghost lanes weightless
    int pc = (p_ < MPATHS) ? p_ : (MPATHS - 1);
    float sgn = 1.0f; int row = pc;
    if (pc >= MC) { sgn = -1.0f; row -= MC; }
    const float* __restrict__ zrow  = z  + (size_t)row * NSTEPS;
    const float* __restrict__ z1row = z1 + (size_t)row * NSTEPS;

    const float hh   = 1.0f / 360.0f;
    const float sqh  = sqrtf(hh);
    const float s75  = 0.86602540378443864676f;
    const float rate = 0.025f;

    float S = 100.0f, V = 0.04f;

    #pragma unroll 1
    for (int i = 0; i < NSTEPS; ++i) {
        const float zcr = zrow[i];
        const float z1r = z1row[i];
        const float dW  = sqh * (sgn * zcr);
        const float dW1 = sqh * (sgn * (-0.5f * zcr + s75 * z1r));
        const float t   = (float)i * hh;

        const unsigned in01 = pkrtz(t, S);     // (t, S)
        const unsigned in23 = pkrtz(V, rate);  // (V, rate)

        float dS = 0.0f, dV = 0.0f;

        #pragma unroll 1   // net loop rolled: body fits I$
        for (int net = 0; net < 4; ++net) {
            const float* __restrict__ b1n = b1 + net * 64;
            const float* __restrict__ b2n = b2 + net * 64;
            const float* __restrict__ won = Wo + net * 64;
            const uint4* __restrict__ wl1 = &wlds[net * 32];
            const uint4* __restrict__ wl2 = &wlds[128 + net * 512];

            // ---- layer 1: 1 b128 read = 2 neurons' weights ----
            u32x32 h1p;
            #pragma unroll
            for (int u = 0; u < 64; u += 2) {
                const uint4 wv = wl1[u >> 1];   // [w(u,01) w(u,23) w(u+1,01) w(u+1,23)]
                float a0 = fdot2(wv.x, in01, b1n[u]);
                a0 = fdot2(wv.y, in23, a0);
                float a1 = fdot2(wv.z, in01, b1n[u + 1]);
                a1 = fdot2(wv.w, in23, a1);
                h1p[u >> 1] = pkrtz(fmaxf(a0, 0.0f), fmaxf(a1, 0.0f));
            }

            // ---- layer 2: per 4-neuron group, 32 b128 reads + 128 dot2 ----
            float outn = bo[net];
            #pragma unroll
            for (int j = 0; j < 64; j += 4) {
                const uint4* __restrict__ r0 = wl2 + (j + 0) * 8;
                const uint4* __restrict__ r1 = wl2 + (j + 1) * 8;
                const uint4* __restrict__ r2 = wl2 + (j + 2) * 8;
                const uint4* __restrict__ r3 = wl2 + (j + 3) * 8;
                float a0 = b2n[j + 0];
                float a1 = b2n[j + 1];
                float a2 = b2n[j + 2];
                float a3 = b2n[j + 3];
                #pragma unroll
                for (int kk = 0; kk < 8; ++kk) {
                    const uint4 w0 = r0[kk];
                    const uint4 w1 = r1[kk];
                    const uint4 w2 = r2[kk];
                    const uint4 w3 = r3[kk];
                    const unsigned h0 = h1p[4 * kk + 0];
                    const unsigned h1 = h1p[4 * kk + 1];
                    const unsigned h2 = h1p[4 * kk + 2];
                    const unsigned h3 = h1p[4 * kk + 3];
                    a0 = fdot2(w0.x, h0, a0); a0 = fdot2(w0.y, h1, a0);
                    a0 = fdot2(w0.z, h2, a0); a0 = fdot2(w0.w, h3, a0);
                    a1 = fdot2(w1.x, h0, a1); a1 = fdot2(w1.y, h1, a1);
                    a1 = fdot2(w1.z, h2, a1); a1 = fdot2(w1.w, h3, a1);
                    a2 = fdot2(w2.x, h0, a2); a2 = fdot2(w2.y, h1, a2);
                    a2 = fdot2(w2.z, h2, a2); a2 = fdot2(w2.w, h3, a2);
                    a3 = fdot2(w3.x, h0, a3); a3 = fdot2(w3.y, h1, a3);
                    a3 = fdot2(w3.z, h2, a3); a3 = fdot2(w3.w, h3, a3);
                }
                outn = fmaf(won[j + 0], fmaxf(a0, 0.0f), outn);
                outn = fmaf(won[j + 1], fmaxf(a1, 0.0f), outn);
                outn = fmaf(won[j + 2], fmaxf(a2, 0.0f), outn);
                outn = fmaf(won[j + 3], fmaxf(a3, 0.0f), outn);
            }

            // route: 0=driftS, 1=diffS, 2=driftV, 3=diffV
            const float ms = (net == 0) ? hh : (net == 1) ? dW  : 0.0f;
            const float mv = (net == 2) ? hh : (net == 3) ? dW1 : 0.0f;
            dS = fmaf(outn, ms, dS);
            dV = fmaf(outn, mv, dV);
        }

        S = fmaxf(S + dS, 0.0f);
        V = fmaxf(V + dV, 0.0f);

        // ---- on-the-fly payoff at maturities (each wave: its own 64 paths) --
        int mm = maskTab[i + 1];
        while (mm) {
            int qq = __ffs(mm) - 1; mm &= mm - 1;
            float pay = wgt * fmaxf(S - ls_k[qq], 0.0f);
            #pragma unroll
            for (int off = 32; off > 0; off >>= 1)
                pay += __shfl_down(pay, off, 64);
            if (lane == 0) atomicAdd(&acc[qq], pay);
        }
    }
}

__global__ void price_kernel(const float* __restrict__ x,
                             const float* __restrict__ acc,
                             float* __restrict__ out)
{
    const int q = threadIdx.x;
    if (q < NOPTS) {
        const float mat = x[q * 2];
        const float disc = expf((-0.025f * mat) / 360.0f);
        out[q] = acc[q] * (1.0f / (float)MPATHS) * disc;
    }
}

extern "C" void kernel_launch(void* const* d_in, const int* in_sizes, int n_in,
                              void* d_out, int out_size, void* d_ws, size_t ws_size,
                              hipStream_t stream)
{
    const float* x  = (const float*)d_in[0];
    const float* z  = (const float*)d_in[1];
    const float* z1 = (const float*)d_in[2];
    const float* W1 = (const float*)d_in[3];
    const float* b1 = (const float*)d_in[4];
    const float* W2 = (const float*)d_in[5];
    const float* b2 = (const float*)d_in[6];
    const float* Wo = (const float*)d_in[7];
    const float* bo = (const float*)d_in[8];

    float*    acc = (float*)d_ws;                      // 128B accumulators
    unsigned* wp1 = (unsigned*)((char*)d_ws + 256);    // 2KB  packed W1 (16B-aligned)
    unsigned* wp2 = wp1 + 512;                         // 32KB packed W2 (16B-aligned)

    (void)hipMemsetAsync(acc, 0, NOPTS * sizeof(float), stream);
    pack_w<<<(512 + 8192 + 255) / 256, 256, 0, stream>>>(W1, W2, wp1, wp2);

    const int grid = (MPATHS + 255) / 256;   // 391 blocks x 4 independent waves
    sde_dot2<<<grid, 256, 0, stream>>>(x, z, z1, b1, b2, Wo, bo, wp1, wp2, acc);
    price_kernel<<<1, 64, 0, stream>>>(x, acc, (float*)d_out);
}

// Round 9
// 8464.753 us; speedup vs baseline: 1.2535x; 1.0893x over previous
//
#include <hip/hip_runtime.h>
#include <math.h>

#define MC      50000
#define MPATHS  100000   // 2*MC antithetic
#define NSTEPS  180
#define NOPTS   32

typedef _Float16 half2v __attribute__((ext_vector_type(2)));
typedef unsigned u32x32 __attribute__((ext_vector_type(32)));

// v_dot2_f32_f16: c += a.x*b.x + a.y*b.y (per-lane, layout-free)
static __device__ __forceinline__ float fdot2(unsigned w, unsigned h, float c) {
    return __builtin_amdgcn_fdot2(__builtin_bit_cast(half2v, w),
                                  __builtin_bit_cast(half2v, h), c, false);
}
// RNE f16 pair pack (pre-kernel only)
static __device__ __forceinline__ unsigned pkh2(float a, float b) {
    half2v h; h.x = (_Float16)a; h.y = (_Float16)b;   // .x = low half
    return __builtin_bit_cast(unsigned, h);
}
// fast RTZ pack (main loop, per-step inputs)
static __device__ __forceinline__ unsigned pkrtz(float a, float b) {
    auto h = __builtin_amdgcn_cvt_pkrtz(a, b);
    return __builtin_bit_cast(unsigned, h);
}

// pack W1 (4x64x4) and W2 (4x64x64) f32 -> f16x2 pairs (natural pair order)
__global__ void pack_w(const float* __restrict__ W1, const float* __restrict__ W2,
                       unsigned* __restrict__ wp1, unsigned* __restrict__ wp2) {
    int i = blockIdx.x * 256 + threadIdx.x;
    if (i < 512)              wp1[i] = pkh2(W1[2 * i], W1[2 * i + 1]);
    else if (i < 512 + 8192) { int k = i - 512; wp2[k] = pkh2(W2[2 * k], W2[2 * k + 1]); }
}

// Block = 1 wave = 64 lanes x 2 paths/lane (R=2). Weights staged in LDS once;
// each uint4 weight read now feeds 8 dot2 (2 paths) -> VALU:LDS issue 2:1,
// LDS pipe fully hidden. j-loop rolled (I$); no barriers in step loop.
__global__ __launch_bounds__(64, 2)
void sde_dot2(const float* __restrict__ x,
              const float* __restrict__ z,
              const float* __restrict__ z1,
              const float* __restrict__ b1, const float* __restrict__ b2,
              const float* __restrict__ Wo, const float* __restrict__ bo,
              const uint4* __restrict__ wp1,
              const uint4* __restrict__ wp2,
              float* __restrict__ acc)
{
    // [0,128): W1 pairs (net n at n*32) ; [128,2176): W2 (net n row j at 128+n*512+j*8)
    __shared__ __align__(16) uint4 wlds[2176];
    __shared__ float ls_k[NOPTS];
    __shared__ int   maskTab[NSTEPS + 4];

    const int tid = threadIdx.x;

    // ---- stage weights + option table (once per block) ----
    for (int j = tid; j < 2176; j += 64)
        wlds[j] = (j < 128) ? wp1[j] : wp2[j - 128];
    for (int jj = tid; jj < NSTEPS + 4; jj += 64) maskTab[jj] = 0;
    if (tid < NOPTS) ls_k[tid] = x[2 * tid + 1];
    __syncthreads();
    if (tid < NOPTS) atomicOr(&maskTab[(int)x[2 * tid]], 1 << tid);
    __syncthreads();

    // ---- two paths per lane ----
    const int pA = blockIdx.x * 128 + tid;
    const int pB = pA + 64;
    const float wgtA = (pA < MPATHS) ? 1.0f : 0.0f;
    const float wgtB = (pB < MPATHS) ? 1.0f : 0.0f;
    int pcA = (pA < MPATHS) ? pA : (MPATHS - 1);
    int pcB = (pB < MPATHS) ? pB : (MPATHS - 1);
    float sgnA = 1.0f, sgnB = 1.0f;
    int rowA = pcA, rowB = pcB;
    if (pcA >= MC) { sgnA = -1.0f; rowA -= MC; }
    if (pcB >= MC) { sgnB = -1.0f; rowB -= MC; }
    const float* __restrict__ zA  = z  + (size_t)rowA * NSTEPS;
    const float* __restrict__ z1A = z1 + (size_t)rowA * NSTEPS;
    const float* __restrict__ zB  = z  + (size_t)rowB * NSTEPS;
    const float* __restrict__ z1B = z1 + (size_t)rowB * NSTEPS;

    const float hh   = 1.0f / 360.0f;
    const float sqh  = sqrtf(hh);
    const float s75  = 0.86602540378443864676f;
    const float rate = 0.025f;

    float SA = 100.0f, VA = 0.04f;
    float SB = 100.0f, VB = 0.04f;

    #pragma unroll 1
    for (int i = 0; i < NSTEPS; ++i) {
        const float zcrA = zA[i],  z1rA = z1A[i];
        const float zcrB = zB[i],  z1rB = z1B[i];
        const float dWA  = sqh * (sgnA * zcrA);
        const float dW1A = sqh * (sgnA * (-0.5f * zcrA + s75 * z1rA));
        const float dWB  = sqh * (sgnB * zcrB);
        const float dW1B = sqh * (sgnB * (-0.5f * zcrB + s75 * z1rB));
        const float t    = (float)i * hh;

        const unsigned inA01 = pkrtz(t, SA), inA23 = pkrtz(VA, rate);
        const unsigned inB01 = pkrtz(t, SB), inB23 = pkrtz(VB, rate);

        float dSA = 0.0f, dVA = 0.0f, dSB = 0.0f, dVB = 0.0f;

        #pragma unroll 1   // net loop rolled
        for (int net = 0; net < 4; ++net) {
            const float* __restrict__ b1n = b1 + net * 64;
            const float* __restrict__ b2n = b2 + net * 64;
            const float* __restrict__ won = Wo + net * 64;
            const uint4* __restrict__ wl1 = &wlds[net * 32];
            const uint4* __restrict__ wl2 = &wlds[128 + net * 512];

            // ---- layer 1: 1 b128 read = 2 neurons' weights, 2 paths ----
            u32x32 hA, hB;
            #pragma unroll
            for (int u = 0; u < 64; u += 2) {
                const uint4 wv = wl1[u >> 1];
                const float bb0 = b1n[u], bb1 = b1n[u + 1];
                float a0 = fdot2(wv.x, inA01, bb0); a0 = fdot2(wv.y, inA23, a0);
                float a1 = fdot2(wv.z, inA01, bb1); a1 = fdot2(wv.w, inA23, a1);
                float c0 = fdot2(wv.x, inB01, bb0); c0 = fdot2(wv.y, inB23, c0);
                float c1 = fdot2(wv.z, inB01, bb1); c1 = fdot2(wv.w, inB23, c1);
                hA[u >> 1] = pkrtz(fmaxf(a0, 0.0f), fmaxf(a1, 0.0f));
                hB[u >> 1] = pkrtz(fmaxf(c0, 0.0f), fmaxf(c1, 0.0f));
            }

            // ---- layer 2 (j rolled for I$) + fused output layer ----
            float outA = bo[net], outB = outA;
            #pragma unroll 1
            for (int j = 0; j < 64; j += 4) {
                const uint4* __restrict__ r0 = wl2 + (j + 0) * 8;
                const uint4* __restrict__ r1 = wl2 + (j + 1) * 8;
                const uint4* __restrict__ r2 = wl2 + (j + 2) * 8;
                const uint4* __restrict__ r3 = wl2 + (j + 3) * 8;
                float a0 = b2n[j], a1 = b2n[j + 1], a2 = b2n[j + 2], a3 = b2n[j + 3];
                float c0 = a0, c1 = a1, c2 = a2, c3 = a3;
                #pragma unroll
                for (int kk = 0; kk < 8; ++kk) {
                    const uint4 w0 = r0[kk];
                    const uint4 w1 = r1[kk];
                    const uint4 w2 = r2[kk];
                    const uint4 w3 = r3[kk];
                    const unsigned hA0 = hA[4 * kk], hA1 = hA[4 * kk + 1];
                    const unsigned hA2 = hA[4 * kk + 2], hA3 = hA[4 * kk + 3];
                    const unsigned hB0 = hB[4 * kk], hB1 = hB[4 * kk + 1];
                    const unsigned hB2 = hB[4 * kk + 2], hB3 = hB[4 * kk + 3];
                    a0 = fdot2(w0.x, hA0, a0); a0 = fdot2(w0.y, hA1, a0);
                    a0 = fdot2(w0.z, hA2, a0); a0 = fdot2(w0.w, hA3, a0);
                    a1 = fdot2(w1.x, hA0, a1); a1 = fdot2(w1.y, hA1, a1);
                    a1 = fdot2(w1.z, hA2, a1); a1 = fdot2(w1.w, hA3, a1);
                    a2 = fdot2(w2.x, hA0, a2); a2 = fdot2(w2.y, hA1, a2);
                    a2 = fdot2(w2.z, hA2, a2); a2 = fdot2(w2.w, hA3, a2);
                    a3 = fdot2(w3.x, hA0, a3); a3 = fdot2(w3.y, hA1, a3);
                    a3 = fdot2(w3.z, hA2, a3); a3 = fdot2(w3.w, hA3, a3);
                    c0 = fdot2(w0.x, hB0, c0); c0 = fdot2(w0.y, hB1, c0);
                    c0 = fdot2(w0.z, hB2, c0); c0 = fdot2(w0.w, hB3, c0);
                    c1 = fdot2(w1.x, hB0, c1); c1 = fdot2(w1.y, hB1, c1);
                    c1 = fdot2(w1.z, hB2, c1); c1 = fdot2(w1.w, hB3, c1);
                    c2 = fdot2(w2.x, hB0, c2); c2 = fdot2(w2.y, hB1, c2);
                    c2 = fdot2(w2.z, hB2, c2); c2 = fdot2(w2.w, hB3, c2);
                    c3 = fdot2(w3.x, hB0, c3); c3 = fdot2(w3.y, hB1, c3);
                    c3 = fdot2(w3.z, hB2, c3); c3 = fdot2(w3.w, hB3, c3);
                }
                const float wo0 = won[j], wo1 = won[j + 1];
                const float wo2 = won[j + 2], wo3 = won[j + 3];
                outA = fmaf(wo0, fmaxf(a0, 0.0f), outA);
                outA = fmaf(wo1, fmaxf(a1, 0.0f), outA);
                outA = fmaf(wo2, fmaxf(a2, 0.0f), outA);
                outA = fmaf(wo3, fmaxf(a3, 0.0f), outA);
                outB = fmaf(wo0, fmaxf(c0, 0.0f), outB);
                outB = fmaf(wo1, fmaxf(c1, 0.0f), outB);
                outB = fmaf(wo2, fmaxf(c2, 0.0f), outB);
                outB = fmaf(wo3, fmaxf(c3, 0.0f), outB);
            }

            // route: 0=driftS, 1=diffS, 2=driftV, 3=diffV
            const float msA = (net == 0) ? hh : (net == 1) ? dWA  : 0.0f;
            const float mvA = (net == 2) ? hh : (net == 3) ? dW1A : 0.0f;
            const float msB = (net == 0) ? hh : (net == 1) ? dWB  : 0.0f;
            const float mvB = (net == 2) ? hh : (net == 3) ? dW1B : 0.0f;
            dSA = fmaf(outA, msA, dSA);
            dVA = fmaf(outA, mvA, dVA);
            dSB = fmaf(outB, msB, dSB);
            dVB = fmaf(outB, mvB, dVB);
        }

        SA = fmaxf(SA + dSA, 0.0f);
        VA = fmaxf(VA + dVA, 0.0f);
        SB = fmaxf(SB + dSB, 0.0f);
        VB = fmaxf(VB + dVB, 0.0f);

        // ---- on-the-fly payoff at maturities (both paths summed per lane) --
        int mm = maskTab[i + 1];
        while (mm) {
            int qq = __ffs(mm) - 1; mm &= mm - 1;
            float pay = wgtA * fmaxf(SA - ls_k[qq], 0.0f)
                      + wgtB * fmaxf(SB - ls_k[qq], 0.0f);
            #pragma unroll
            for (int off = 32; off > 0; off >>= 1)
                pay += __shfl_down(pay, off, 64);
            if (tid == 0) atomicAdd(&acc[qq], pay);
        }
    }
}

__global__ void price_kernel(const float* __restrict__ x,
                             const float* __restrict__ acc,
                             float* __restrict__ out)
{
    const int q = threadIdx.x;
    if (q < NOPTS) {
        const float mat = x[q * 2];
        const float disc = expf((-0.025f * mat) / 360.0f);
        out[q] = acc[q] * (1.0f / (float)MPATHS) * disc;
    }
}

extern "C" void kernel_launch(void* const* d_in, const int* in_sizes, int n_in,
                              void* d_out, int out_size, void* d_ws, size_t ws_size,
                              hipStream_t stream)
{
    const float* x  = (const float*)d_in[0];
    const float* z  = (const float*)d_in[1];
    const float* z1 = (const float*)d_in[2];
    const float* W1 = (const float*)d_in[3];
    const float* b1 = (const float*)d_in[4];
    const float* W2 = (const float*)d_in[5];
    const float* b2 = (const float*)d_in[6];
    const float* Wo = (const float*)d_in[7];
    const float* bo = (const float*)d_in[8];

    float*    acc = (float*)d_ws;                      // 128B accumulators
    unsigned* wp1 = (unsigned*)((char*)d_ws + 256);    // 2KB  packed W1 (16B-aligned)
    unsigned* wp2 = wp1 + 512;                         // 32KB packed W2 (16B-aligned)

    (void)hipMemsetAsync(acc, 0, NOPTS * sizeof(float), stream);
    pack_w<<<(512 + 8192 + 255) / 256, 256, 0, stream>>>(W1, W2, wp1, wp2);

    const int grid = (MPATHS + 127) / 128;   // 782 blocks x 1 wave x 2 paths/lane
    sde_dot2<<<grid, 64, 0, stream>>>(x, z, z1, b1, b2, Wo, bo,
                                      (const uint4*)wp1, (const uint4*)wp2, acc);
    price_kernel<<<1, 64, 0, stream>>>(x, acc, (float*)d_out);
}

// Round 10
// 3110.212 us; speedup vs baseline: 3.4116x; 2.7216x over previous
//
#include <hip/hip_runtime.h>
#include <math.h>

#define MC      50000
#define MPATHS  100000
#define NSTEPS  180
#define NOPTS   32

typedef __attribute__((ext_vector_type(8))) short short8;
typedef __attribute__((ext_vector_type(4))) float float4v;
typedef _Float16 half2v __attribute__((ext_vector_type(2)));
typedef unsigned u32x32 __attribute__((ext_vector_type(32)));

// ---------- helpers ----------
static __device__ __forceinline__ unsigned bf16u(float x) {        // RNE
    unsigned u = __float_as_uint(x);
    return (u + 0x7fffu + ((u >> 16) & 1u)) >> 16;
}
static __device__ __forceinline__ float bf16val(float x) {
    return __uint_as_float(bf16u(x) << 16);
}
static __device__ __forceinline__ unsigned pkh2(float a, float b) { // f16 pair (fallback path)
    half2v h; h.x = (_Float16)a; h.y = (_Float16)b;
    return __builtin_bit_cast(unsigned, h);
}
static __device__ __forceinline__ unsigned pkrtz(float a, float b) {
    auto h = __builtin_amdgcn_cvt_pkrtz(a, b);
    return __builtin_bit_cast(unsigned, h);
}
static __device__ __forceinline__ float fdot2(unsigned w, unsigned h, float c) {
    return __builtin_amdgcn_fdot2(__builtin_bit_cast(half2v, w),
                                  __builtin_bit_cast(half2v, h), c, false);
}
static __device__ __forceinline__ short8 fr4(unsigned a, unsigned b,
                                             unsigned c, unsigned d) {
    union { unsigned u[4]; short8 s; } t;
    t.u[0] = a; t.u[1] = b; t.u[2] = c; t.u[3] = d;
    return t.s;
}
static __device__ __forceinline__ float4v mfma16(short8 a, short8 b, float4v c) {
    return __builtin_amdgcn_mfma_f32_16x16x32_bf16(a, b, c, 0, 0, 0);
}

// ws table region (ints): [0..511]=mA  [512..1023]=kA(kid->rank)
//                          [1024..1535]=nB  [1536..2047]=kB(kid->rank)

// ---------- probe 1: m-map (A) and n-map (B); trusts only C/D layout ----------
__global__ void probe_mn(int* tbl) {
    const int lane = threadIdx.x;
    for (int s = lane; s < 2048; s += 64) tbl[s] = 0;   // defaults (safe clamp later)
    const float4v z4 = {0.f, 0.f, 0.f, 0.f};
    for (int L = 0; L < 64; ++L)
        for (int j = 0; j < 8; ++j) {
            unsigned au[4] = {0u, 0u, 0u, 0u};
            if (lane == L) au[j >> 1] = 0x3F80u << (16 * (j & 1));
            short8 a = fr4(au[0], au[1], au[2], au[3]);
            short8 b = fr4(0x3F803F80u, 0x3F803F80u, 0x3F803F80u, 0x3F803F80u);
            float4v d = mfma16(a, b, z4);
            if ((lane & 15) == 0) {
                #pragma unroll
                for (int r = 0; r < 4; ++r)
                    if (d[r] != 0.0f) tbl[L * 8 + j] = (lane >> 4) * 4 + r;
            }
        }
    for (int L = 0; L < 64; ++L)
        for (int j = 0; j < 8; ++j) {
            unsigned bu[4] = {0u, 0u, 0u, 0u};
            if (lane == L) bu[j >> 1] = 0x3F80u << (16 * (j & 1));
            short8 a = fr4(0x3F803F80u, 0x3F803F80u, 0x3F803F80u, 0x3F803F80u);
            short8 b = fr4(bu[0], bu[1], bu[2], bu[3]);
            float4v d = mfma16(a, b, z4);
            if ((lane >> 4) == 0 && d[0] != 0.0f) tbl[1024 + L * 8 + j] = (lane & 15);
        }
}

// ---------- probe 2: k-equivalence classes between A-slots and B-slots ----------
__global__ void probe_k(int* tbl) {
    const int lane = threadIdx.x;
    const int sA = blockIdx.x;              // 0..511
    const float4v z4 = {0.f, 0.f, 0.f, 0.f};
    unsigned au[4] = {0u, 0u, 0u, 0u};
    if (lane == (sA >> 3)) au[(sA & 7) >> 1] = 0x3F80u << (16 * (sA & 1));
    short8 a = fr4(au[0], au[1], au[2], au[3]);
    int kid = -1;
    for (int sB = 0; sB < 512; ++sB) {
        unsigned bu[4] = {0u, 0u, 0u, 0u};
        const int LB = sB >> 3, jB = sB & 7;
        if (lane == LB) bu[jB >> 1] = 0x3F80u << (16 * (jB & 1));
        short8 b = fr4(bu[0], bu[1], bu[2], bu[3]);
        float4v d = mfma16(a, b, z4);
        bool hit = (d[0] != 0.f) | (d[1] != 0.f) | (d[2] != 0.f) | (d[3] != 0.f);
        if (__any(hit)) {
            if (kid < 0) kid = sB;
            if (lane == 0) tbl[1536 + sB] = kid;   // benign same-value races
        }
    }
    if (lane == 0) tbl[512 + sA] = (kid < 0) ? 0 : kid;
}

// ---------- probe 3: rank k-classes; verify full layout stack; write flag ----------
__global__ void finalize_verify(int* tbl, int* flag) {
    const int lane = threadIdx.x;
    int rA[8], rB[8];
    #pragma unroll
    for (int j = 0; j < 8; ++j) {
        const int s = lane * 8 + j;
        const int kidA = tbl[512 + s], kidB = tbl[1536 + s];
        int ra = 0, rb = 0;
        for (int u = 0; u < 512; ++u) {
            const int canon = (tbl[1536 + u] == u);
            ra += canon & (u < kidA);
            rb += canon & (u < kidB);
        }
        rA[j] = ra & 31; rB[j] = rb & 31;
    }
    __syncthreads();
    #pragma unroll
    for (int j = 0; j < 8; ++j) {
        tbl[512 + lane * 8 + j]  = rA[j];
        tbl[1536 + lane * 8 + j] = rB[j];
    }
    // verify: integer GEMM through discovered tables, exact compare
    unsigned au[4] = {0u, 0u, 0u, 0u}, bu[4] = {0u, 0u, 0u, 0u};
    #pragma unroll
    for (int j = 0; j < 8; ++j) {
        const int s = lane * 8 + j;
        const int m = tbl[s] & 15, ka = rA[j];
        const int n = tbl[1024 + s] & 15, kb = rB[j];
        const int fv = ((m * 7 + ka * 3) % 5) - 2;
        const int gv = ((kb * 5 + n * 11) % 7) - 3;
        au[j >> 1] |= bf16u((float)fv) << (16 * (j & 1));
        bu[j >> 1] |= bf16u((float)gv) << (16 * (j & 1));
    }
    const float4v z4 = {0.f, 0.f, 0.f, 0.f};
    float4v d = mfma16(fr4(au[0], au[1], au[2], au[3]),
                       fr4(bu[0], bu[1], bu[2], bu[3]), z4);
    const int col = lane & 15;
    bool ok = true;
    #pragma unroll
    for (int r = 0; r < 4; ++r) {
        const int row = (lane >> 4) * 4 + r;
        int ref = 0;
        for (int k = 0; k < 32; ++k)
            ref += (((row * 7 + k * 3) % 5) - 2) * (((k * 5 + col * 11) % 7) - 3);
        ok = ok && (d[r] == (float)ref);
    }
    const bool allok = __all(ok);
    if (lane == 0) *flag = allok ? 1 : 0;
}

// ---------- build W1/W2 A-fragment tables (after verify tables final) ----------
__global__ void build_frags(const float* __restrict__ W1, const float* __restrict__ b1,
                            const float* __restrict__ W2, const int* __restrict__ tbl,
                            uint4* __restrict__ w1f, uint4* __restrict__ w2f) {
    const int t = blockIdx.x * 256 + threadIdx.x;   // 0..3071
    if (t >= 3072) return;
    const int lane = t & 63, frag = t >> 6;
    const float rateB = bf16val(0.025f);
    unsigned u[4] = {0u, 0u, 0u, 0u};
    if (frag < 16) {            // W1: net=frag>>2, mt=frag&3 ; k 0..5 hi, 6..11 lo-residual
        const int net = frag >> 2, mt = frag & 3;
        #pragma unroll
        for (int j = 0; j < 8; ++j) {
            const int s = lane * 8 + j;
            const int m = tbl[s] & 15, k = tbl[512 + s] & 31;
            unsigned bits = 0u;
            if (k < 12) {
                const int kk = (k < 6) ? k : k - 6;
                const int M = net * 64 + 16 * mt + m;
                float v;
                if (kk == 0)                 v = W1[M * 4 + 0];
                else if (kk == 1 || kk == 4) v = W1[M * 4 + 1];
                else if (kk == 2 || kk == 5) v = W1[M * 4 + 2];
                else                         v = W1[M * 4 + 3] + b1[M] / rateB;
                bits = (k < 6) ? bf16u(v) : bf16u(v - bf16val(v));
            }
            u[j >> 1] |= bits << (16 * (j & 1));
        }
        w1f[frag * 64 + lane] = make_uint4(u[0], u[1], u[2], u[3]);
    } else {                    // W2: f2=frag-16: net=f2>>3, mt=(f2>>1)&3, kc=f2&1
        const int f2 = frag - 16;
        const int net = f2 >> 3, mt = (f2 >> 1) & 3, kc = f2 & 1;
        #pragma unroll
        for (int j = 0; j < 8; ++j) {
            const int s = lane * 8 + j;
            const int m = tbl[s] & 15, k = tbl[512 + s] & 31;
            const float v = W2[(net * 64 + 16 * mt + m) * 64 + 32 * kc + k];
            u[j >> 1] |= bf16u(v) << (16 * (j & 1));
        }
        w2f[f2 * 64 + lane] = make_uint4(u[0], u[1], u[2], u[3]);
    }
}

// ---------- main MFMA path-sim: 782 blocks x 2 independent waves x 64 paths ----------
__global__ __launch_bounds__(128)
void sde_mfma2(const float* __restrict__ x, const float* __restrict__ z,
               const float* __restrict__ z1, const float* __restrict__ b2,
               const float* __restrict__ Wo, const float* __restrict__ bo,
               const int* __restrict__ tbl, const uint4* __restrict__ w1f,
               const uint4* __restrict__ w2f, const int* __restrict__ flag,
               float* __restrict__ acc)
{
    if (*flag != 1) return;
    __shared__ float    INs[2][7 * 65];
    __shared__ unsigned Hs[2][32 * 66];
    __shared__ __align__(16) float wo_s[256];
    __shared__ __align__(16) float b2_s[256];
    __shared__ float ls_k[NOPTS];
    __shared__ int   maskTab[NSTEPS + 4];

    const int tid = threadIdx.x;
    const int wv = tid >> 6, lane = tid & 63;
    const int q = lane >> 4, c = lane & 15;

    for (int j = tid; j < 256; j += 128) { wo_s[j] = Wo[j]; b2_s[j] = b2[j]; }
    for (int j = tid; j < NSTEPS + 4; j += 128) maskTab[j] = 0;
    if (tid < NOPTS) ls_k[tid] = x[2 * tid + 1];
    INs[wv][3 * 65 + lane] = bf16val(0.025f);   // rate row (constant)
    INs[wv][6 * 65 + lane] = 0.0f;              // zero row (k>=12)
    __syncthreads();
    if (tid < NOPTS) atomicOr(&maskTab[(int)x[2 * tid]], 1 << tid);
    __syncthreads();

    // per-lane B-placement addressing from discovered tables
    int rowj[8], vbj[8]; unsigned shj[8];
    #pragma unroll
    for (int j = 0; j < 8; ++j) {
        const int s = lane * 8 + j;
        const int kb = tbl[1536 + s] & 31;
        const int nb = tbl[1024 + s] & 15;
        const int row = (kb < 6) ? kb : ((kb < 12) ? kb - 6 : 6);
        rowj[j] = row * 65 + nb;                // INs index (u32)
        vbj[j]  = (kb >> 1) * 66 + nb;          // Hs index (u32)
        shj[j]  = (unsigned)((kb & 1) * 16);
    }

    const int p_ = blockIdx.x * 128 + tid;
    const float wgt = (p_ < MPATHS) ? 1.0f : 0.0f;
    int pc = (p_ < MPATHS) ? p_ : (MPATHS - 1);
    float sgn = 1.0f; int row_ = pc;
    if (pc >= MC) { sgn = -1.0f; row_ -= MC; }
    const float* __restrict__ zrow  = z  + (size_t)row_ * NSTEPS;
    const float* __restrict__ z1row = z1 + (size_t)row_ * NSTEPS;

    const float hh = 1.0f / 360.0f, sqh = sqrtf(hh);
    const float s75 = 0.86602540378443864676f;
    const float4v z4 = {0.f, 0.f, 0.f, 0.f};

    float S = 100.0f, V = 0.04f;

    #pragma unroll 1
    for (int i = 0; i < NSTEPS; ++i) {
        const float zcr = zrow[i], z1r = z1row[i];
        const float dW  = sqh * (sgn * zcr);
        const float dW1 = sqh * (sgn * (-0.5f * zcr + s75 * z1r));
        const float t = (float)i * hh;

        const float Sh = bf16val(S), Vh = bf16val(V);
        INs[wv][0 * 65 + lane] = bf16val(t);
        INs[wv][1 * 65 + lane] = Sh;
        INs[wv][2 * 65 + lane] = Vh;
        INs[wv][4 * 65 + lane] = S - Sh;
        INs[wv][5 * 65 + lane] = V - Vh;

        // layer-1 B frags (shared by the 4 nets)
        unsigned B1[4][4];
        #pragma unroll
        for (int nt = 0; nt < 4; ++nt) {
            unsigned v[8];
            #pragma unroll
            for (int j = 0; j < 8; ++j)
                v[j] = __float_as_uint(INs[wv][rowj[j] + nt * 16]) >> 16;
            B1[nt][0] = v[0] | (v[1] << 16);
            B1[nt][1] = v[2] | (v[3] << 16);
            B1[nt][2] = v[4] | (v[5] << 16);
            B1[nt][3] = v[6] | (v[7] << 16);
        }

        float dS = 0.0f, dV = 0.0f;

        #pragma unroll 1
        for (int net = 0; net < 4; ++net) {
            // ---- layer 1 MFMA -> relu -> bf16 pack -> Hs (C/D trusted) ----
            #pragma unroll
            for (int mt = 0; mt < 4; ++mt) {
                const uint4 af = w1f[(net * 4 + mt) * 64 + lane];
                const short8 A = fr4(af.x, af.y, af.z, af.w);
                #pragma unroll
                for (int nt = 0; nt < 4; ++nt) {
                    float4v d = mfma16(A, fr4(B1[nt][0], B1[nt][1], B1[nt][2], B1[nt][3]), z4);
                    const float r0 = fmaxf(d[0], 0.f), r1 = fmaxf(d[1], 0.f);
                    const float r2 = fmaxf(d[2], 0.f), r3 = fmaxf(d[3], 0.f);
                    const unsigned pk0 = (__float_as_uint(r0) >> 16) |
                                         (__float_as_uint(r1) & 0xFFFF0000u);
                    const unsigned pk1 = (__float_as_uint(r2) >> 16) |
                                         (__float_as_uint(r3) & 0xFFFF0000u);
                    const int base = (8 * mt + 2 * q) * 66 + 16 * nt + c;
                    Hs[wv][base]      = pk0;
                    Hs[wv][base + 66] = pk1;
                }
            }
            // ---- gather L2 B frags from Hs via discovered placement ----
            unsigned B2[4][2][4];
            #pragma unroll
            for (int nt = 0; nt < 4; ++nt)
                #pragma unroll
                for (int kc = 0; kc < 2; ++kc)
                    #pragma unroll
                    for (int jp = 0; jp < 4; ++jp) {
                        const unsigned r0 = Hs[wv][vbj[2 * jp]     + kc * 1056 + nt * 16];
                        const unsigned r1 = Hs[wv][vbj[2 * jp + 1] + kc * 1056 + nt * 16];
                        B2[nt][kc][jp] = ((r0 >> shj[2 * jp]) & 0xFFFFu) |
                                         (((r1 >> shj[2 * jp + 1]) & 0xFFFFu) << 16);
                    }
            // ---- layer 2 MFMA + fused epilogue ----
            float part[4] = {0.f, 0.f, 0.f, 0.f};
            #pragma unroll
            for (int mt = 0; mt < 4; ++mt) {
                const uint4 a0 = w2f[((net * 4 + mt) * 2 + 0) * 64 + lane];
                const uint4 a1 = w2f[((net * 4 + mt) * 2 + 1) * 64 + lane];
                const short8 A0 = fr4(a0.x, a0.y, a0.z, a0.w);
                const short8 A1 = fr4(a1.x, a1.y, a1.z, a1.w);
                const float4 wo4 = *(const float4*)&wo_s[net * 64 + 16 * mt + 4 * q];
                const float4 b24 = *(const float4*)&b2_s[net * 64 + 16 * mt + 4 * q];
                #pragma unroll
                for (int nt = 0; nt < 4; ++nt) {
                    float4v d = mfma16(A0, fr4(B2[nt][0][0], B2[nt][0][1], B2[nt][0][2], B2[nt][0][3]), z4);
                    d = mfma16(A1, fr4(B2[nt][1][0], B2[nt][1][1], B2[nt][1][2], B2[nt][1][3]), d);
                    part[nt] += wo4.x * fmaxf(d[0] + b24.x, 0.f)
                              + wo4.y * fmaxf(d[1] + b24.y, 0.f)
                              + wo4.z * fmaxf(d[2] + b24.z, 0.f)
                              + wo4.w * fmaxf(d[3] + b24.w, 0.f);
                }
            }
            #pragma unroll
            for (int nt = 0; nt < 4; ++nt) {
                float s = part[nt];
                s += __shfl_xor(s, 16, 64);
                s += __shfl_xor(s, 32, 64);
                part[nt] = s;
            }
            float o = (q == 0) ? part[0] : (q == 1) ? part[1] : (q == 2) ? part[2] : part[3];
            o += bo[net];
            const float ms = (net == 0) ? hh : (net == 1) ? dW  : 0.0f;
            const float mv = (net == 2) ? hh : (net == 3) ? dW1 : 0.0f;
            dS = fmaf(o, ms, dS);
            dV = fmaf(o, mv, dV);
        }

        S = fmaxf(S + dS, 0.0f);
        V = fmaxf(V + dV, 0.0f);

        int mm = maskTab[i + 1];
        while (mm) {
            const int qq = __ffs(mm) - 1; mm &= mm - 1;
            float pay = wgt * fmaxf(S - ls_k[qq], 0.0f);
            #pragma unroll
            for (int off = 32; off > 0; off >>= 1)
                pay += __shfl_down(pay, off, 64);
            if (lane == 0) atomicAdd(&acc[qq], pay);
        }
    }
}

// ---------- fallback: round-9 dot2 kernel (proven), gated on !flag ----------
__global__ void pack_w(const float* __restrict__ W1, const float* __restrict__ W2,
                       unsigned* __restrict__ wp1, unsigned* __restrict__ wp2) {
    int i = blockIdx.x * 256 + threadIdx.x;
    if (i < 512)              wp1[i] = pkh2(W1[2 * i], W1[2 * i + 1]);
    else if (i < 512 + 8192) { int k = i - 512; wp2[k] = pkh2(W2[2 * k], W2[2 * k + 1]); }
}

__global__ __launch_bounds__(64, 2)
void sde_dot2(const float* __restrict__ x, const float* __restrict__ z,
              const float* __restrict__ z1, const float* __restrict__ b1,
              const float* __restrict__ b2, const float* __restrict__ Wo,
              const float* __restrict__ bo, const uint4* __restrict__ wp1,
              const uint4* __restrict__ wp2, const int* __restrict__ flag,
              float* __restrict__ acc)
{
    if (*flag == 1) return;
    __shared__ __align__(16) uint4 wlds[2176];
    __shared__ float ls_k[NOPTS];
    __shared__ int   maskTab[NSTEPS + 4];
    const int tid = threadIdx.x;
    for (int j = tid; j < 2176; j += 64) wlds[j] = (j < 128) ? wp1[j] : wp2[j - 128];
    for (int jj = tid; jj < NSTEPS + 4; jj += 64) maskTab[jj] = 0;
    if (tid < NOPTS) ls_k[tid] = x[2 * tid + 1];
    __syncthreads();
    if (tid < NOPTS) atomicOr(&maskTab[(int)x[2 * tid]], 1 << tid);
    __syncthreads();
    const int pA = blockIdx.x * 128 + tid, pB = pA + 64;
    const float wgtA = (pA < MPATHS) ? 1.0f : 0.0f;
    const float wgtB = (pB < MPATHS) ? 1.0f : 0.0f;
    int pcA = (pA < MPATHS) ? pA : (MPATHS - 1);
    int pcB = (pB < MPATHS) ? pB : (MPATHS - 1);
    float sgnA = 1.0f, sgnB = 1.0f; int rowA = pcA, rowB = pcB;
    if (pcA >= MC) { sgnA = -1.0f; rowA -= MC; }
    if (pcB >= MC) { sgnB = -1.0f; rowB -= MC; }
    const float* __restrict__ zA  = z  + (size_t)rowA * NSTEPS;
    const float* __restrict__ z1A = z1 + (size_t)rowA * NSTEPS;
    const float* __restrict__ zB  = z  + (size_t)rowB * NSTEPS;
    const float* __restrict__ z1B = z1 + (size_t)rowB * NSTEPS;
    const float hh = 1.0f / 360.0f, sqh = sqrtf(hh);
    const float s75 = 0.86602540378443864676f, rate = 0.025f;
    float SA = 100.0f, VA = 0.04f, SB = 100.0f, VB = 0.04f;
    #pragma unroll 1
    for (int i = 0; i < NSTEPS; ++i) {
        const float zcrA = zA[i], z1rA = z1A[i], zcrB = zB[i], z1rB = z1B[i];
        const float dWA = sqh * (sgnA * zcrA);
        const float dW1A = sqh * (sgnA * (-0.5f * zcrA + s75 * z1rA));
        const float dWB = sqh * (sgnB * zcrB);
        const float dW1B = sqh * (sgnB * (-0.5f * zcrB + s75 * z1rB));
        const float t = (float)i * hh;
        const unsigned inA01 = pkrtz(t, SA), inA23 = pkrtz(VA, rate);
        const unsigned inB01 = pkrtz(t, SB), inB23 = pkrtz(VB, rate);
        float dSA = 0.f, dVA = 0.f, dSB = 0.f, dVB = 0.f;
        #pragma unroll 1
        for (int net = 0; net < 4; ++net) {
            const float* __restrict__ b1n = b1 + net * 64;
            const float* __restrict__ b2n = b2 + net * 64;
            const float* __restrict__ won = Wo + net * 64;
            const uint4* __restrict__ wl1 = &wlds[net * 32];
            const uint4* __restrict__ wl2 = &wlds[128 + net * 512];
            u32x32 hA, hB;
            #pragma unroll
            for (int u = 0; u < 64; u += 2) {
                const uint4 wv = wl1[u >> 1];
                const float bb0 = b1n[u], bb1 = b1n[u + 1];
                float a0 = fdot2(wv.x, inA01, bb0); a0 = fdot2(wv.y, inA23, a0);
                float a1 = fdot2(wv.z, inA01, bb1); a1 = fdot2(wv.w, inA23, a1);
                float c0 = fdot2(wv.x, inB01, bb0); c0 = fdot2(wv.y, inB23, c0);
                float c1 = fdot2(wv.z, inB01, bb1); c1 = fdot2(wv.w, inB23, c1);
                hA[u >> 1] = pkrtz(fmaxf(a0, 0.f), fmaxf(a1, 0.f));
                hB[u >> 1] = pkrtz(fmaxf(c0, 0.f), fmaxf(c1, 0.f));
            }
            float outA = bo[net], outB = outA;
            #pragma unroll 1
            for (int j = 0; j < 64; j += 4) {
                const uint4* __restrict__ r0 = wl2 + (j + 0) * 8;
                const uint4* __restrict__ r1 = wl2 + (j + 1) * 8;
                const uint4* __restrict__ r2 = wl2 + (j + 2) * 8;
                const uint4* __restrict__ r3 = wl2 + (j + 3) * 8;
                float a0 = b2n[j], a1 = b2n[j + 1], a2 = b2n[j + 2], a3 = b2n[j + 3];
                float c0 = a0, c1 = a1, c2 = a2, c3 = a3;
                #pragma unroll
                for (int kk = 0; kk < 8; ++kk) {
                    const uint4 w0 = r0[kk], w1 = r1[kk], w2 = r2[kk], w3 = r3[kk];
                    const unsigned hA0 = hA[4 * kk], hA1 = hA[4 * kk + 1];
                    const unsigned hA2 = hA[4 * kk + 2], hA3 = hA[4 * kk + 3];
                    const unsigned hB0 = hB[4 * kk], hB1 = hB[4 * kk + 1];
                    const unsigned hB2 = hB[4 * kk + 2], hB3 = hB[4 * kk + 3];
                    a0 = fdot2(w0.x, hA0, a0); a0 = fdot2(w0.y, hA1, a0);
                    a0 = fdot2(w0.z, hA2, a0); a0 = fdot2(w0.w, hA3, a0);
                    a1 = fdot2(w1.x, hA0, a1); a1 = fdot2(w1.y, hA1, a1);
                    a1 = fdot2(w1.z, hA2, a1); a1 = fdot2(w1.w, hA3, a1);
                    a2 = fdot2(w2.x, hA0, a2); a2 = fdot2(w2.y, hA1, a2);
                    a2 = fdot2(w2.z, hA2, a2); a2 = fdot2(w2.w, hA3, a2);
                    a3 = fdot2(w3.x, hA0, a3); a3 = fdot2(w3.y, hA1, a3);
                    a3 = fdot2(w3.z, hA2, a3); a3 = fdot2(w3.w, hA3, a3);
                    c0 = fdot2(w0.x, hB0, c0); c0 = fdot2(w0.y, hB1, c0);
                    c0 = fdot2(w0.z, hB2, c0); c0 = fdot2(w0.w, hB3, c0);
                    c1 = fdot2(w1.x, hB0, c1); c1 = fdot2(w1.y, hB1, c1);
                    c1 = fdot2(w1.z, hB2, c1); c1 = fdot2(w1.w, hB3, c1);
                    c2 = fdot2(w2.x, hB0, c2); c2 = fdot2(w2.y, hB1, c2);
                    c2 = fdot2(w2.z, hB2, c2); c2 = fdot2(w2.w, hB3, c2);
                    c3 = fdot2(w3.x, hB0, c3); c3 = fdot2(w3.y, hB1, c3);
                    c3 = fdot2(w3.z, hB2, c3); c3 = fdot2(w3.w, hB3, c3);
                }
                const float wo0 = won[j], wo1 = won[j + 1];
                const float wo2 = won[j + 2], wo3 = won[j + 3];
                outA = fmaf(wo0, fmaxf(a0, 0.f), outA); outA = fmaf(wo1, fmaxf(a1, 0.f), outA);
                outA = fmaf(wo2, fmaxf(a2, 0.f), outA); outA = fmaf(wo3, fmaxf(a3, 0.f), outA);
                outB = fmaf(wo0, fmaxf(c0, 0.f), outB); outB = fmaf(wo1, fmaxf(c1, 0.f), outB);
                outB = fmaf(wo2, fmaxf(c2, 0.f), outB); outB = fmaf(wo3, fmaxf(c3, 0.f), outB);
            }
            const float msA = (net == 0) ? hh : (net == 1) ? dWA  : 0.0f;
            const float mvA = (net == 2) ? hh : (net == 3) ? dW1A : 0.0f;
            const float msB = (net == 0) ? hh : (net == 1) ? dWB  : 0.0f;
            const float mvB = (net == 2) ? hh : (net == 3) ? dW1B : 0.0f;
            dSA = fmaf(outA, msA, dSA); dVA = fmaf(outA, mvA, dVA);
            dSB = fmaf(outB, msB, dSB); dVB = fmaf(outB, mvB, dVB);
        }
        SA = fmaxf(SA + dSA, 0.f); VA = fmaxf(VA + dVA, 0.f);
        SB = fmaxf(SB + dSB, 0.f); VB = fmaxf(VB + dVB, 0.f);
        int mm = maskTab[i + 1];
        while (mm) {
            const int qq = __ffs(mm) - 1; mm &= mm - 1;
            float pay = wgtA * fmaxf(SA - ls_k[qq], 0.f) + wgtB * fmaxf(SB - ls_k[qq], 0.f);
            #pragma unroll
            for (int off = 32; off > 0; off >>= 1)
                pay += __shfl_down(pay, off, 64);
            if (tid == 0) atomicAdd(&acc[qq], pay);
        }
    }
}

__global__ void price_kernel(const float* __restrict__ x, const float* __restrict__ acc,
                             float* __restrict__ out) {
    const int q = threadIdx.x;
    if (q < NOPTS) {
        const float mat = x[q * 2];
        out[q] = acc[q] * (1.0f / (float)MPATHS) * expf((-0.025f * mat) / 360.0f);
    }
}

extern "C" void kernel_launch(void* const* d_in, const int* in_sizes, int n_in,
                              void* d_out, int out_size, void* d_ws, size_t ws_size,
                              hipStream_t stream)
{
    const float* x  = (const float*)d_in[0];
    const float* z  = (const float*)d_in[1];
    const float* z1 = (const float*)d_in[2];
    const float* W1 = (const float*)d_in[3];
    const float* b1 = (const float*)d_in[4];
    const float* W2 = (const float*)d_in[5];
    const float* b2 = (const float*)d_in[6];
    const float* Wo = (const float*)d_in[7];
    const float* bo = (const float*)d_in[8];

    char* ws = (char*)d_ws;
    float*    acc  = (float*)ws;                 // 128 B
    int*      flag = (int*)(ws + 256);
    int*      tbl  = (int*)(ws + 1024);          // 8 KB tables
    uint4*    w1f  = (uint4*)(ws + 16384);       // 16 KB
    uint4*    w2f  = (uint4*)(ws + 32768);       // 32 KB
    unsigned* wp1  = (unsigned*)(ws + 65536);    // 2 KB
    unsigned* wp2  = wp1 + 512;                  // 32 KB

    (void)hipMemsetAsync(acc, 0, NOPTS * sizeof(float), stream);
    pack_w<<<(512 + 8192 + 255) / 256, 256, 0, stream>>>(W1, W2, wp1, wp2);
    probe_mn<<<1, 64, 0, stream>>>(tbl);
    probe_k<<<512, 64, 0, stream>>>(tbl);
    finalize_verify<<<1, 64, 0, stream>>>(tbl, flag);
    build_frags<<<12, 256, 0, stream>>>(W1, b1, W2, tbl, w1f, w2f);

    const int grid = (MPATHS + 127) / 128;   // 782
    sde_mfma2<<<grid, 128, 0, stream>>>(x, z, z1, b2, Wo, bo, tbl, w1f, w2f, flag, acc);
    sde_dot2<<<grid, 64, 0, stream>>>(x, z, z1, b1, b2, Wo, bo,
                                      (const uint4*)wp1, (const uint4*)wp2, flag, acc);
    price_kernel<<<1, 64, 0, stream>>>(x, acc, (float*)d_out);
}